// Round 1
// baseline (555.951 us; speedup 1.0000x reference)
//
#include <hip/hip_runtime.h>

#define N_ROWS   131072
#define M_PROTO  512
#define D_DIM    64
#define OUT_R1   8388608
#define OUT_R2   8388609
#define OUT_R3   8388610
#define OUT_LAT  8388611
#define BIGVAL   1000000.0f

// ---------------- init: colmin = +inf bits, accumulators = 0 ----------------
__global__ __launch_bounds__(512) void init_kernel(int* __restrict__ colmin,
                                                   float* __restrict__ acc) {
    colmin[threadIdx.x] = 0x7F800000;  // +inf as positive-float int ordering
    if (threadIdx.x == 0) { acc[0] = 0.f; acc[1] = 0.f; }
}

// ---------------- prep: copy x -> out, XX[r] = ||x_r||^2 --------------------
__global__ __launch_bounds__(256) void prep_kernel(const float* __restrict__ x,
                                                   float* __restrict__ outx,
                                                   float* __restrict__ XX) {
    const int ln  = threadIdx.x & 63;
    const int wv  = threadIdx.x >> 6;
    const int row = blockIdx.x * 4 + wv;
    const size_t base = (size_t)row * 64 + ln;
    const float v = x[base];
    outx[base] = v;
    float s = v * v;
    #pragma unroll
    for (int sh = 1; sh < 64; sh <<= 1) s += __shfl_xor(s, sh, 64);
    if (ln == 0) XX[row] = s;
}

// ------- proto: PP[j] = ||p_j||^2 (sequential chain), R3 row-mins -----------
// diag of p2p = 2*(PP_seq - dot_tree): different summation orders -> generically
// tiny nonzero, replicating the reference's norm+matmul-trick behavior.
__global__ __launch_bounds__(256) void proto_kernel(const float* __restrict__ p,
                                                    float* __restrict__ PP,
                                                    float* __restrict__ acc) {
    const int j  = blockIdx.x;
    const int ln = threadIdx.x & 63;
    const int wv = threadIdx.x >> 6;
    const float* prow = p + j * 64;
    const float pjl = prow[ln];          // per-lane element of row j
    float pp = 0.f;                      // wave-uniform sequential FMA chain
    #pragma unroll
    for (int k = 0; k < 64; ++k) { const float t = prow[k]; pp = fmaf(t, t, pp); }
    float rmin = INFINITY;
    for (int jp = wv; jp < M_PROTO; jp += 4) {
        float t = pjl * p[jp * 64 + ln];
        #pragma unroll
        for (int sh = 1; sh < 64; sh <<= 1) t += __shfl_xor(t, sh, 64); // tree dot
        float d = fmaf(-2.f, t, pp + pp);
        if (d == 0.0f) d = BIGVAL;       // exact-zero mask, as in reference
        rmin = fminf(rmin, d);
    }
    __shared__ float sm[4];
    if (ln == 0) sm[wv] = rmin;
    __syncthreads();
    if (threadIdx.x == 0) {
        const float m = fminf(fminf(sm[0], sm[1]), fminf(sm[2], sm[3]));
        atomicAdd(&acc[1], m);
        PP[j] = pp;
    }
}

// ---------------- main fused: d_fp + row mins + col mins --------------------
// 512 threads = 8 waves; thread j owns prototype column j in 64 VGPRs.
// x rows are block-uniform -> scalar (s_load) reads; dot = v_fmac(VGPR, SGPR).
__global__ __launch_bounds__(512, 4) void main_kernel(const float* __restrict__ x,
                                                      const float* __restrict__ p,
                                                      const float* __restrict__ XX,
                                                      const float* __restrict__ PP,
                                                      float* __restrict__ lat,
                                                      int* __restrict__ colmin,
                                                      float* __restrict__ acc) {
    const int j  = threadIdx.x;          // column 0..511
    const int ln = j & 63;
    const int wv = j >> 6;
    float4 pj[16];
    {
        const float4* p4 = (const float4*)(p + (size_t)j * 64);
        #pragma unroll
        for (int q = 0; q < 16; ++q) pj[q] = p4[q];
    }
    const float ppj = PP[j];
    float cmin = INFINITY;
    __shared__ float rp[256 * 8];
    __shared__ float sm8[8];
    const int r0 = blockIdx.x * 256;
    for (int rr = 0; rr < 256; ++rr) {
        const int r = r0 + rr;
        const float4* xr = (const float4*)(x + (size_t)r * 64);
        float a0 = 0.f;
        #pragma unroll
        for (int q = 0; q < 16; ++q) {
            const float4 xq = xr[q];     // uniform -> SGPR
            a0 = fmaf(pj[q].x, xq.x, a0);
            a0 = fmaf(pj[q].y, xq.y, a0);
            a0 = fmaf(pj[q].z, xq.z, a0);
            a0 = fmaf(pj[q].w, xq.w, a0);
        }
        const float dval = XX[r] + ppj - 2.f * a0;
        lat[(size_t)r * 512 + j] = dval; // coalesced 256B per wave
        cmin = fminf(cmin, dval);
        float m = dval;                  // wave-level row min
        #pragma unroll
        for (int sh = 1; sh < 64; sh <<= 1) m = fminf(m, __shfl_xor(m, sh, 64));
        if (ln == 0) rp[rr * 8 + wv] = m;
    }
    atomicMin(colmin + j, __float_as_int(cmin));  // positive floats: int-ordered
    __syncthreads();
    float s = 0.f;
    if (j < 256) {
        float m = rp[j * 8 + 0];
        #pragma unroll
        for (int q = 1; q < 8; ++q) m = fminf(m, rp[j * 8 + q]);
        s = m;
    }
    #pragma unroll
    for (int sh = 1; sh < 64; sh <<= 1) s += __shfl_xor(s, sh, 64);
    if (ln == 0) sm8[wv] = s;
    __syncthreads();
    if (j == 0) {
        float t = 0.f;
        #pragma unroll
        for (int q = 0; q < 8; ++q) t += sm8[q];
        atomicAdd(&acc[0], t);           // sum of row-mins for this block
    }
}

// ---------------- finalize: scalars --------------------------------------
__global__ __launch_bounds__(512) void finalize_kernel(const int* __restrict__ colmin,
                                                       const float* __restrict__ acc,
                                                       float* __restrict__ out) {
    const int t  = threadIdx.x;
    const int ln = t & 63, wv = t >> 6;
    float s = __int_as_float(colmin[t]);
    #pragma unroll
    for (int sh = 1; sh < 64; sh <<= 1) s += __shfl_xor(s, sh, 64);
    __shared__ float sm[8];
    if (ln == 0) sm[wv] = s;
    __syncthreads();
    if (t == 0) {
        float tot = 0.f;
        #pragma unroll
        for (int q = 0; q < 8; ++q) tot += sm[q];
        out[OUT_R1] = tot / 512.f;
        out[OUT_R2] = acc[0] / 131072.f;
        out[OUT_R3] = acc[1] / 512.f;
    }
}

extern "C" void kernel_launch(void* const* d_in, const int* in_sizes, int n_in,
                              void* d_out, int out_size, void* d_ws, size_t ws_size,
                              hipStream_t stream) {
    const float* x = (const float*)d_in[0];
    const float* p = (const float*)d_in[1];
    float* out = (float*)d_out;
    float* ws  = (float*)d_ws;
    int*   colmin = (int*)d_ws;            // [512] ints
    float* acc    = ws + 512;              // acc[0]=R2 sum, acc[1]=R3 sum
    float* XX     = ws + 1024;             // [131072]
    float* PP     = ws + 1024 + N_ROWS;    // [512]
    float* lat    = out + OUT_LAT;

    hipLaunchKernelGGL(init_kernel,     dim3(1),     dim3(512), 0, stream, colmin, acc);
    hipLaunchKernelGGL(prep_kernel,     dim3(32768), dim3(256), 0, stream, x, out, XX);
    hipLaunchKernelGGL(proto_kernel,    dim3(512),   dim3(256), 0, stream, p, PP, acc);
    hipLaunchKernelGGL(main_kernel,     dim3(512),   dim3(512), 0, stream, x, p, XX, PP, lat, colmin, acc);
    hipLaunchKernelGGL(finalize_kernel, dim3(1),     dim3(512), 0, stream, colmin, acc, out);
}

// Round 3
// 438.442 us; speedup vs baseline: 1.2680x; 1.2680x over previous
//
#include <hip/hip_runtime.h>
#include <hip/hip_bf16.h>

#define N_ROWS   131072
#define M_PROTO  512
#define OUT_R1   8388608
#define OUT_R2   8388609
#define OUT_R3   8388610
#define OUT_LAT  8388611
#define BIGVAL   1000000.0f

typedef __attribute__((ext_vector_type(8))) short bf16x8;   // 8 bf16 (4 VGPRs)
typedef __attribute__((ext_vector_type(4))) float f32x4;    // 4 f32 acc

static __device__ __forceinline__ unsigned short f2bf(float f) {
    __hip_bfloat16 h = __float2bfloat16(f);     // RNE convert
    return __builtin_bit_cast(unsigned short, h);
}

// ---------------- init: colmin = +inf bits, accumulators = 0 ----------------
__global__ __launch_bounds__(512) void init_kernel(int* __restrict__ colmin,
                                                   float* __restrict__ acc) {
    colmin[threadIdx.x] = 0x7F800000;
    if (threadIdx.x == 0) { acc[0] = 0.f; acc[1] = 0.f; }
}

// ------- proto: PP[j] = ||p_j||^2 (sequential chain), R3 row-mins -----------
// Verified correct in round 1 (R3 matched) — byte-identical logic kept.
__global__ __launch_bounds__(256) void proto_kernel(const float* __restrict__ p,
                                                    float* __restrict__ PP,
                                                    float* __restrict__ acc) {
    const int j  = blockIdx.x;
    const int ln = threadIdx.x & 63;
    const int wv = threadIdx.x >> 6;
    const float* prow = p + j * 64;
    const float pjl = prow[ln];
    float pp = 0.f;
    #pragma unroll
    for (int k = 0; k < 64; ++k) { const float t = prow[k]; pp = fmaf(t, t, pp); }
    float rmin = INFINITY;
    for (int jp = wv; jp < M_PROTO; jp += 4) {
        float t = pjl * p[jp * 64 + ln];
        #pragma unroll
        for (int sh = 1; sh < 64; sh <<= 1) t += __shfl_xor(t, sh, 64);
        float d = fmaf(-2.f, t, pp + pp);
        if (d == 0.0f) d = BIGVAL;
        rmin = fminf(rmin, d);
    }
    __shared__ float sm[4];
    if (ln == 0) sm[wv] = rmin;
    __syncthreads();
    if (threadIdx.x == 0) {
        const float m = fminf(fminf(sm[0], sm[1]), fminf(sm[2], sm[3]));
        atomicAdd(&acc[1], m);
        PP[j] = pp;
    }
}

// ---------------- main: bf16 MFMA, fused x-copy + XX + lat + mins -----------
// Block: 512 thr = 8 waves (4 row-groups x 2 col-groups). Tile 64 rows x 512 cols.
// A/B frags loaded with IDENTICAL (e, lane>>4)->k map (k = 8*(l>>4)+e): any HW
// k-permutation cancels in the contraction. C/D: row=(l>>4)*4+i, col=l&15 (m89).
// LDS rows are 128 B -> T2 XOR swizzle byte ^= (row&7)<<4 on write AND read.
__global__ __launch_bounds__(512, 4) void main_kernel(const float* __restrict__ x,
                                                      const float* __restrict__ p,
                                                      const float* __restrict__ PP,
                                                      float* __restrict__ outx,
                                                      float* __restrict__ lat,
                                                      int* __restrict__ colmin_g,
                                                      float* __restrict__ acc_g) {
    __shared__ __align__(16) unsigned char Al[64 * 128];    // 8 KB  (64 rows bf16)
    __shared__ __align__(16) unsigned char Bl[512 * 128];   // 64 KB (512 cols bf16)
    __shared__ float xx_lds[64];
    __shared__ float pp_lds[512];
    __shared__ int   cmin_lds[512];
    __shared__ float rmin_lds[2][64];

    const int tid = threadIdx.x;
    const int l   = tid & 63;
    const int w   = tid >> 6;
    const int rg  = w >> 1;        // row-group 0..3 (16 rows each)
    const int cg  = w & 1;         // col-group 0..1 (256 cols each)

    cmin_lds[tid] = 0x7F800000;
    pp_lds[tid]   = PP[tid];

    // ---- stage x: copy to out, XX per row, bf16 -> Al (swizzled) ----
    {
        const float4* x4 = (const float4*)x + (size_t)blockIdx.x * 1024;
        float4*       o4 = (float4*)outx   + (size_t)blockIdx.x * 1024;
        #pragma unroll
        for (int rep = 0; rep < 2; ++rep) {
            const int idx = rep * 512 + tid;
            const int row = idx >> 4, seg = idx & 15;
            const float4 v = x4[idx];
            o4[idx] = v;
            float sq = v.x * v.x + v.y * v.y + v.z * v.z + v.w * v.w;
            const unsigned int lo = (unsigned int)f2bf(v.x) | ((unsigned int)f2bf(v.y) << 16);
            const unsigned int hi = (unsigned int)f2bf(v.z) | ((unsigned int)f2bf(v.w) << 16);
            const int byte = (row * 128 + seg * 8) ^ ((row & 7) << 4);
            *(uint2*)(Al + byte) = make_uint2(lo, hi);
            #pragma unroll
            for (int sh = 1; sh < 16; sh <<= 1) sq += __shfl_xor(sq, sh, 64);
            if ((l & 15) == 0) xx_lds[row] = sq;    // row = rep*32 + w*4 + (l>>4)
        }
    }
    // ---- stage p: bf16 -> Bl (swizzled); p row-major == B [col][k] ----
    {
        const float4* p4 = (const float4*)p;
        #pragma unroll
        for (int it = 0; it < 16; ++it) {
            const int idx = it * 512 + tid;
            const int col = idx >> 4, seg = idx & 15;
            const float4 v = p4[idx];
            const unsigned int lo = (unsigned int)f2bf(v.x) | ((unsigned int)f2bf(v.y) << 16);
            const unsigned int hi = (unsigned int)f2bf(v.z) | ((unsigned int)f2bf(v.w) << 16);
            const int byte = (col * 128 + seg * 8) ^ ((col & 7) << 4);
            *(uint2*)(Bl + byte) = make_uint2(lo, hi);
        }
    }
    __syncthreads();

    // ---- MFMA: wave tile 16 rows x 256 cols = 16 col-tiles, K=64 (2 steps) --
    f32x4 acc[16];
    #pragma unroll
    for (int i = 0; i < 16; ++i) acc[i] = (f32x4){0.f, 0.f, 0.f, 0.f};
    const int arow = rg * 16 + (l & 15);
    const int kb   = (l >> 4) * 16;                 // 16B = 8 bf16 = k 8b..8b+7
    const int aswz = (arow & 7) << 4;
    const bf16x8 a0 = *(const bf16x8*)(Al + ((arow * 128      + kb) ^ aswz));
    const bf16x8 a1 = *(const bf16x8*)(Al + ((arow * 128 + 64 + kb) ^ aswz));
    #pragma unroll
    for (int ct = 0; ct < 16; ++ct) {
        const int col  = cg * 256 + ct * 16 + (l & 15);
        const int bswz = (col & 7) << 4;
        const bf16x8 b0 = *(const bf16x8*)(Bl + ((col * 128      + kb) ^ bswz));
        const bf16x8 b1 = *(const bf16x8*)(Bl + ((col * 128 + 64 + kb) ^ bswz));
        acc[ct] = __builtin_amdgcn_mfma_f32_16x16x32_bf16(a0, b0, acc[ct], 0, 0, 0);
        acc[ct] = __builtin_amdgcn_mfma_f32_16x16x32_bf16(a1, b1, acc[ct], 0, 0, 0);
    }

    // ---- epilogue: dval = XX + PP - 2*dot; lat store; row/col mins ----
    const int rloc = rg * 16 + (l >> 4) * 4;        // C rows this lane owns
    float xxr[4];
    #pragma unroll
    for (int i = 0; i < 4; ++i) xxr[i] = xx_lds[rloc + i];
    const size_t rowg0 = (size_t)blockIdx.x * 64 + rloc;
    float rmin[4] = {INFINITY, INFINITY, INFINITY, INFINITY};
    #pragma unroll
    for (int ct = 0; ct < 16; ++ct) {
        const int col = cg * 256 + ct * 16 + (l & 15);
        const float ppc = pp_lds[col];
        float dv[4];
        #pragma unroll
        for (int i = 0; i < 4; ++i) {
            dv[i] = xxr[i] + ppc - 2.f * acc[ct][i];
            lat[(rowg0 + i) * 512 + col] = dv[i];
            rmin[i] = fminf(rmin[i], dv[i]);
        }
        float cm = fminf(fminf(dv[0], dv[1]), fminf(dv[2], dv[3]));
        cm = fminf(cm, __shfl_xor(cm, 16, 64));
        cm = fminf(cm, __shfl_xor(cm, 32, 64));
        if (l < 16) atomicMin(&cmin_lds[col], __float_as_int(cm));
    }
    #pragma unroll
    for (int i = 0; i < 4; ++i) {
        float r = rmin[i];
        #pragma unroll
        for (int sh = 1; sh < 16; sh <<= 1) r = fminf(r, __shfl_xor(r, sh, 64));
        if ((l & 15) == 0) rmin_lds[cg][rloc + i] = r;
    }
    __syncthreads();
    if (tid < 64) {
        float r = fminf(rmin_lds[0][tid], rmin_lds[1][tid]);
        #pragma unroll
        for (int sh = 1; sh < 64; sh <<= 1) r += __shfl_xor(r, sh, 64);
        if (tid == 0) atomicAdd(&acc_g[0], r);
    }
    atomicMin(&colmin_g[tid], cmin_lds[tid]);
}

// ---------------- finalize: scalars --------------------------------------
__global__ __launch_bounds__(512) void finalize_kernel(const int* __restrict__ colmin,
                                                       const float* __restrict__ acc,
                                                       float* __restrict__ out) {
    const int t  = threadIdx.x;
    const int ln = t & 63, wv = t >> 6;
    float s = __int_as_float(colmin[t]);
    #pragma unroll
    for (int sh = 1; sh < 64; sh <<= 1) s += __shfl_xor(s, sh, 64);
    __shared__ float sm[8];
    if (ln == 0) sm[wv] = s;
    __syncthreads();
    if (t == 0) {
        float tot = 0.f;
        #pragma unroll
        for (int q = 0; q < 8; ++q) tot += sm[q];
        out[OUT_R1] = tot / 512.f;
        out[OUT_R2] = acc[0] / 131072.f;
        out[OUT_R3] = acc[1] / 512.f;
    }
}

extern "C" void kernel_launch(void* const* d_in, const int* in_sizes, int n_in,
                              void* d_out, int out_size, void* d_ws, size_t ws_size,
                              hipStream_t stream) {
    const float* x = (const float*)d_in[0];
    const float* p = (const float*)d_in[1];
    float* out = (float*)d_out;
    int*   colmin = (int*)d_ws;               // [512]
    float* acc    = (float*)d_ws + 512;       // [2] : R2 sum, R3 sum
    float* PP     = (float*)d_ws + 1024;      // [512]
    float* lat    = out + OUT_LAT;

    hipLaunchKernelGGL(init_kernel,     dim3(1),    dim3(512), 0, stream, colmin, acc);
    hipLaunchKernelGGL(proto_kernel,    dim3(512),  dim3(256), 0, stream, p, PP, acc);
    hipLaunchKernelGGL(main_kernel,     dim3(2048), dim3(512), 0, stream,
                       x, p, PP, out, lat, colmin, acc);
    hipLaunchKernelGGL(finalize_kernel, dim3(1),    dim3(512), 0, stream, colmin, acc, out);
}

// Round 4
// 414.000 us; speedup vs baseline: 1.3429x; 1.0590x over previous
//
#include <hip/hip_runtime.h>
#include <hip/hip_bf16.h>

#define N_ROWS   131072
#define M_PROTO  512
#define OUT_R1   8388608
#define OUT_R2   8388609
#define OUT_R3   8388610
#define OUT_LAT  8388611
#define BIGVAL   1000000.0f

typedef __attribute__((ext_vector_type(8)))  short bf16x8;   // 8 bf16 (4 VGPRs)
typedef __attribute__((ext_vector_type(16))) float f32x16;   // 32x32 C/D frag

static __device__ __forceinline__ unsigned int f2bf(float f) {
    __hip_bfloat16 h = __float2bfloat16(f);     // RNE convert
    return (unsigned int)__builtin_bit_cast(unsigned short, h);
}

// ---------------- init: colmin = +inf bits, accumulators = 0 ----------------
__global__ __launch_bounds__(512) void init_kernel(int* __restrict__ colmin,
                                                   float* __restrict__ acc) {
    colmin[threadIdx.x] = 0x7F800000;
    if (threadIdx.x == 0) { acc[0] = 0.f; acc[1] = 0.f; }
}

// --- proto: PP[j] = ||p_j||^2, R3 row-mins (verified), + bf16 B pre-swizzle --
// Bbf layout: byte (col*128 + seg*8) ^ ((col&7)<<4)  == main's LDS image, so
// main stages it with plain 16B copies (write/read swizzle identical).
__global__ __launch_bounds__(256) void proto_kernel(const float* __restrict__ p,
                                                    float* __restrict__ PP,
                                                    float* __restrict__ acc,
                                                    unsigned char* __restrict__ Bbf) {
    const int j  = blockIdx.x;
    const int ln = threadIdx.x & 63;
    const int wv = threadIdx.x >> 6;
    const float* prow = p + j * 64;
    const float pjl = prow[ln];
    float pp = 0.f;
    #pragma unroll
    for (int k = 0; k < 64; ++k) { const float t = prow[k]; pp = fmaf(t, t, pp); }
    float rmin = INFINITY;
    for (int jp = wv; jp < M_PROTO; jp += 4) {
        float t = pjl * p[jp * 64 + ln];
        #pragma unroll
        for (int sh = 1; sh < 64; sh <<= 1) t += __shfl_xor(t, sh, 64);
        float d = fmaf(-2.f, t, pp + pp);
        if (d == 0.0f) d = BIGVAL;
        rmin = fminf(rmin, d);
    }
    __shared__ float sm[4];
    if (ln == 0) sm[wv] = rmin;
    __syncthreads();
    if (threadIdx.x == 0) {
        const float m = fminf(fminf(sm[0], sm[1]), fminf(sm[2], sm[3]));
        atomicAdd(&acc[1], m);
        PP[j] = pp;
    }
    if (threadIdx.x < 16) {
        const int seg = threadIdx.x;
        const float4 v = ((const float4*)p)[j * 16 + seg];
        const unsigned int lo = f2bf(v.x) | (f2bf(v.y) << 16);
        const unsigned int hi = f2bf(v.z) | (f2bf(v.w) << 16);
        const int byte = (j * 128 + seg * 8) ^ ((j & 7) << 4);
        *(uint2*)(Bbf + byte) = make_uint2(lo, hi);
    }
}

// ---------------- main: 32x32x16 bf16 MFMA, full-line lat stores ------------
// 512 thr = 8 waves = 2 row-groups (32 rows) x 4 col-groups (128 cols).
// Block tile 64 rows x 512 cols. A/B frags: identical (lane,e)->k map
// (k = s*16 + (l>>5)*8 + e) -> any HW k-permutation cancels. C/D (m74/m101):
// col = lane&31, row = (reg&3) + 8*(reg>>2) + 4*(lane>>5). Each store = 2 full
// 128B lines. LDS rows 128B -> XOR swizzle byte ^= (row&7)<<4 both sides.
__global__ __launch_bounds__(512, 4) void main_kernel(const float* __restrict__ x,
                                                      const uint4* __restrict__ Bbf,
                                                      const float* __restrict__ PP,
                                                      float* __restrict__ outx,
                                                      float* __restrict__ lat,
                                                      int* __restrict__ colmin_g,
                                                      float* __restrict__ acc_g) {
    __shared__ __align__(16) unsigned char Al[64 * 128];    // 8 KB
    __shared__ __align__(16) unsigned char Bl[512 * 128];   // 64 KB (pre-swizzled image)
    __shared__ float xx_lds[64];
    __shared__ float pp_lds[512];
    __shared__ int   cmin_lds[512];
    __shared__ float rmin_lds[4][64];

    const int tid = threadIdx.x;
    const int l   = tid & 63;
    const int w   = tid >> 6;
    const int rg  = w >> 2;        // 0..1 : 32-row group
    const int cg  = w & 3;         // 0..3 : 128-col group
    const int h   = l >> 5;        // half-wave
    const int lc  = l & 31;

    cmin_lds[tid] = 0x7F800000;
    pp_lds[tid]   = PP[tid];

    // ---- stage B: straight 16B copies of the pre-swizzled bf16 image ----
    #pragma unroll
    for (int it = 0; it < 8; ++it) {
        const int idx = it * 512 + tid;
        const uint4 v = Bbf[idx];
        *(uint4*)(Bl + idx * 16) = v;
    }
    // ---- stage x: copy to out, XX per row, bf16 -> Al (swizzled) ----
    {
        const float4* x4 = (const float4*)x + (size_t)blockIdx.x * 1024;
        float4*       o4 = (float4*)outx   + (size_t)blockIdx.x * 1024;
        #pragma unroll
        for (int rep = 0; rep < 2; ++rep) {
            const int idx = rep * 512 + tid;
            const int row = idx >> 4, seg = idx & 15;
            const float4 v = x4[idx];
            o4[idx] = v;
            float sq = v.x * v.x + v.y * v.y + v.z * v.z + v.w * v.w;
            const unsigned int lo = f2bf(v.x) | (f2bf(v.y) << 16);
            const unsigned int hi = f2bf(v.z) | (f2bf(v.w) << 16);
            const int byte = (row * 128 + seg * 8) ^ ((row & 7) << 4);
            *(uint2*)(Al + byte) = make_uint2(lo, hi);
            #pragma unroll
            for (int sh = 1; sh < 16; sh <<= 1) sq += __shfl_xor(sq, sh, 64);
            if ((l & 15) == 0) xx_lds[row] = sq;
        }
    }
    __syncthreads();

    // ---- MFMA: per wave 32 rows x 128 cols = 4 tiles of 32x32, K=64 -------
    f32x16 acc[4];
    #pragma unroll
    for (int t = 0; t < 4; ++t)
        #pragma unroll
        for (int i = 0; i < 16; ++i) acc[t][i] = 0.f;

    const int arow  = rg * 32 + lc;
    const int aswz  = (arow & 7) << 4;
    const int abase = arow * 128 + h * 16;
    #pragma unroll
    for (int s = 0; s < 4; ++s) {
        const bf16x8 a = *(const bf16x8*)(Al + ((abase + s * 32) ^ aswz));
        #pragma unroll
        for (int t = 0; t < 4; ++t) {
            const int col = cg * 128 + t * 32 + lc;
            const bf16x8 b = *(const bf16x8*)(Bl + ((col * 128 + h * 16 + s * 32) ^ ((col & 7) << 4)));
            acc[t] = __builtin_amdgcn_mfma_f32_32x32x16_bf16(a, b, acc[t], 0, 0, 0);
        }
    }

    // ---- epilogue: dval; 128B-line stores; row/col mins ----
    float ppc[4];
    #pragma unroll
    for (int t = 0; t < 4; ++t) ppc[t] = pp_lds[cg * 128 + t * 32 + lc];
    const int rbase = rg * 32 + 4 * h;
    float cmv[4] = {INFINITY, INFINITY, INFINITY, INFINITY};
    const size_t latrow0 = (size_t)blockIdx.x * 64;
    #pragma unroll
    for (int i = 0; i < 16; ++i) {
        const int rl = rbase + (i & 3) + 8 * (i >> 2);
        const float xxv = xx_lds[rl];
        float rv = INFINITY;
        float* lrow = lat + (latrow0 + rl) * 512 + cg * 128 + lc;
        #pragma unroll
        for (int t = 0; t < 4; ++t) {
            const float dv = xxv + ppc[t] - 2.f * acc[t][i];
            lrow[t * 32] = dv;
            rv = fminf(rv, dv);
            cmv[t] = fminf(cmv[t], dv);
        }
        #pragma unroll
        for (int sh = 1; sh <= 16; sh <<= 1) rv = fminf(rv, __shfl_xor(rv, sh, 64));
        if (lc == 0) rmin_lds[cg][rl] = rv;
    }
    #pragma unroll
    for (int t = 0; t < 4; ++t) {
        const float c = fminf(cmv[t], __shfl_xor(cmv[t], 32, 64));
        if (h == 0) atomicMin(&cmin_lds[cg * 128 + t * 32 + lc], __float_as_int(c));
    }
    __syncthreads();
    if (tid < 64) {
        float r = fminf(fminf(rmin_lds[0][tid], rmin_lds[1][tid]),
                        fminf(rmin_lds[2][tid], rmin_lds[3][tid]));
        #pragma unroll
        for (int sh = 1; sh < 64; sh <<= 1) r += __shfl_xor(r, sh, 64);
        if (tid == 0) atomicAdd(&acc_g[0], r);
    }
    atomicMin(&colmin_g[tid], cmin_lds[tid]);
}

// ---------------- finalize: scalars --------------------------------------
__global__ __launch_bounds__(512) void finalize_kernel(const int* __restrict__ colmin,
                                                       const float* __restrict__ acc,
                                                       float* __restrict__ out) {
    const int t  = threadIdx.x;
    const int ln = t & 63, wv = t >> 6;
    float s = __int_as_float(colmin[t]);
    #pragma unroll
    for (int sh = 1; sh < 64; sh <<= 1) s += __shfl_xor(s, sh, 64);
    __shared__ float sm[8];
    if (ln == 0) sm[wv] = s;
    __syncthreads();
    if (t == 0) {
        float tot = 0.f;
        #pragma unroll
        for (int q = 0; q < 8; ++q) tot += sm[q];
        out[OUT_R1] = tot / 512.f;
        out[OUT_R2] = acc[0] / 131072.f;
        out[OUT_R3] = acc[1] / 512.f;
    }
}

extern "C" void kernel_launch(void* const* d_in, const int* in_sizes, int n_in,
                              void* d_out, int out_size, void* d_ws, size_t ws_size,
                              hipStream_t stream) {
    const float* x = (const float*)d_in[0];
    const float* p = (const float*)d_in[1];
    float* out = (float*)d_out;
    int*   colmin = (int*)d_ws;                       // [512] ints
    float* acc    = (float*)d_ws + 512;               // [2]
    float* PP     = (float*)d_ws + 1024;              // [512]
    unsigned char* Bbf = (unsigned char*)((float*)d_ws + 4096);  // 64KB, 16B aligned
    float* lat    = out + OUT_LAT;

    hipLaunchKernelGGL(init_kernel,     dim3(1),    dim3(512), 0, stream, colmin, acc);
    hipLaunchKernelGGL(proto_kernel,    dim3(512),  dim3(256), 0, stream, p, PP, acc, Bbf);
    hipLaunchKernelGGL(main_kernel,     dim3(2048), dim3(512), 0, stream,
                       x, (const uint4*)Bbf, PP, out, lat, colmin, acc);
    hipLaunchKernelGGL(finalize_kernel, dim3(1),    dim3(512), 0, stream, colmin, acc, out);
}

// Round 8
// 411.288 us; speedup vs baseline: 1.3517x; 1.0066x over previous
//
#include <hip/hip_runtime.h>
#include <hip/hip_bf16.h>

#define N_ROWS   131072
#define M_PROTO  512
#define OUT_R1   8388608
#define OUT_R2   8388609
#define OUT_R3   8388610
#define OUT_LAT  8388611
#define BIGVAL   1000000.0f
#define INF_BITS 0x7F800000

typedef __attribute__((ext_vector_type(8)))  short bf16x8;   // 8 bf16 (4 VGPRs)
typedef __attribute__((ext_vector_type(16))) float f32x16;   // 32x32 C/D frag

static __device__ __forceinline__ unsigned int f2bf(float f) {
    __hip_bfloat16 h = __float2bfloat16(f);     // RNE convert
    return (unsigned int)__builtin_bit_cast(unsigned short, h);
}

// ---------------- init: colmin = +inf bits, accumulators = 0 ----------------
__global__ __launch_bounds__(512) void init_kernel(int* __restrict__ colmin,
                                                   float* __restrict__ acc) {
    colmin[threadIdx.x] = INF_BITS;
    if (threadIdx.x == 0) { acc[0] = 0.f; acc[1] = 0.f; }
}

// --- proto: PP[j] = ||p_j||^2, R3 row-mins (verified), + bf16 B pre-swizzle --
// Bbf layout: byte (col*128 + seg*8) ^ ((col&7)<<4) == main's LDS image, so
// main stages it with plain 16B copies (write/read swizzle identical).
__global__ __launch_bounds__(256) void proto_kernel(const float* __restrict__ p,
                                                    float* __restrict__ PP,
                                                    float* __restrict__ acc,
                                                    unsigned char* __restrict__ Bbf) {
    const int j  = blockIdx.x;
    const int ln = threadIdx.x & 63;
    const int wv = threadIdx.x >> 6;
    const float* prow = p + j * 64;
    const float pjl = prow[ln];
    float pp = 0.f;
    #pragma unroll
    for (int k = 0; k < 64; ++k) { const float t = prow[k]; pp = fmaf(t, t, pp); }
    float rmin = INFINITY;
    for (int jp = wv; jp < M_PROTO; jp += 4) {
        float t = pjl * p[jp * 64 + ln];
        #pragma unroll
        for (int sh = 1; sh < 64; sh <<= 1) t += __shfl_xor(t, sh, 64);
        float d = fmaf(-2.f, t, pp + pp);
        if (d == 0.0f) d = BIGVAL;
        rmin = fminf(rmin, d);
    }
    __shared__ float sm[4];
    if (ln == 0) sm[wv] = rmin;
    __syncthreads();
    if (threadIdx.x == 0) {
        const float m = fminf(fminf(sm[0], sm[1]), fminf(sm[2], sm[3]));
        atomicAdd(&acc[1], m);
        PP[j] = pp;
    }
    if (threadIdx.x < 16) {
        const int seg = threadIdx.x;
        const float4 v = ((const float4*)p)[j * 16 + seg];
        const unsigned int lo = f2bf(v.x) | (f2bf(v.y) << 16);
        const unsigned int hi = f2bf(v.z) | (f2bf(v.w) << 16);
        const int byte = (j * 128 + seg * 8) ^ ((j & 7) << 4);
        *(uint2*)(Bbf + byte) = make_uint2(lo, hi);
    }
}

// ------------- main: 256 rows/block, 4-iter pipelined, 32x32x16 MFMA --------
// 512 thr = 8 waves = 2 row-groups x 4 col-groups; per-iter tile 64 x 512.
// B staged ONCE per block (amortized 4x). x for iter+1 prefetched into regs
// right after barrier A (T14 issue-early) -> HBM latency hides under MFMA+
// epilogue. C/D (m74/m101): col=lane&31, row=(reg&3)+8*(reg>>2)+4*(lane>>5).
// R5 bug fixed: __syncthreads() between one-time LDS setup (pp_lds et al.)
// and the pre-loop ppc read — was an uninitialized-LDS race across waves.
__global__ __launch_bounds__(512, 4) void main_kernel(const float* __restrict__ x,
                                                      const uint4* __restrict__ Bbf,
                                                      const float* __restrict__ PP,
                                                      float* __restrict__ outx,
                                                      float* __restrict__ lat,
                                                      int* __restrict__ colmin_g,
                                                      float* __restrict__ acc_g) {
    __shared__ __align__(16) unsigned char Bl[512 * 128];   // 64 KB pre-swizzled image
    __shared__ __align__(16) unsigned char Al[64 * 128];    // 8 KB
    __shared__ float xx_lds[64];
    __shared__ float pp_lds[512];
    __shared__ int   cmin_lds[512];
    __shared__ int   rowmin_lds[64];
    __shared__ float rsum_lds[1];

    const int tid = threadIdx.x;
    const int l   = tid & 63;
    const int w   = tid >> 6;
    const int rg  = w >> 2;        // 0..1 : 32-row group
    const int cg  = w & 3;         // 0..3 : 128-col group
    const int h   = l >> 5;        // half-wave
    const int lc  = l & 31;

    // ---- one-time block setup ----
    cmin_lds[tid] = INF_BITS;
    pp_lds[tid]   = PP[tid];
    if (tid < 64) rowmin_lds[tid] = INF_BITS;
    if (tid == 0) rsum_lds[0] = 0.f;
    #pragma unroll
    for (int it = 0; it < 8; ++it) {           // stage B: plain 16B copies
        const int idx = it * 512 + tid;
        *(uint4*)(Bl + idx * 16) = Bbf[idx];
    }

    const size_t x4base = (size_t)blockIdx.x * 4096;   // 256 rows * 16 float4
    const float4* x4 = (const float4*)x;
    float4*       o4 = (float4*)outx;
    float4 xf0 = x4[x4base + tid];                      // iter-0 x in regs
    float4 xf1 = x4[x4base + 512 + tid];

    __syncthreads();               // order setup writes (pp_lds!) before reads

    const int arow  = rg * 32 + lc;
    const int aswz  = (arow & 7) << 4;
    const int abase = arow * 128 + h * 16;
    float ppc[4];
    #pragma unroll
    for (int t = 0; t < 4; ++t) ppc[t] = pp_lds[cg * 128 + t * 32 + lc];

    for (int it = 0; it < 4; ++it) {
        // ---- stage x: Al (swizzled bf16) + outx copy + XX ----
        #pragma unroll
        for (int rep = 0; rep < 2; ++rep) {
            const float4 v   = rep ? xf1 : xf0;
            const int    idx = rep * 512 + tid;
            const int    row = idx >> 4, seg = idx & 15;
            o4[x4base + it * 1024 + idx] = v;
            float sq = v.x * v.x + v.y * v.y + v.z * v.z + v.w * v.w;
            const unsigned int lo = f2bf(v.x) | (f2bf(v.y) << 16);
            const unsigned int hi = f2bf(v.z) | (f2bf(v.w) << 16);
            const int byte = (row * 128 + seg * 8) ^ ((row & 7) << 4);
            *(uint2*)(Al + byte) = make_uint2(lo, hi);
            #pragma unroll
            for (int sh = 1; sh < 16; sh <<= 1) sq += __shfl_xor(sq, sh, 64);
            if ((l & 15) == 0) xx_lds[row] = sq;
        }
        __syncthreads();                       // barrier A

        // ---- prefetch next iter's x (latency hides under MFMA+epilogue) ----
        if (it < 3) {
            xf0 = x4[x4base + (it + 1) * 1024 + tid];
            xf1 = x4[x4base + (it + 1) * 1024 + 512 + tid];
        }

        // ---- MFMA: wave 32 rows x 128 cols = 4 tiles of 32x32, K=64 ----
        f32x16 acc[4];
        #pragma unroll
        for (int t = 0; t < 4; ++t)
            #pragma unroll
            for (int i = 0; i < 16; ++i) acc[t][i] = 0.f;
        #pragma unroll
        for (int s = 0; s < 4; ++s) {
            const bf16x8 a = *(const bf16x8*)(Al + ((abase + s * 32) ^ aswz));
            #pragma unroll
            for (int t = 0; t < 4; ++t) {
                const int col = cg * 128 + t * 32 + lc;
                const bf16x8 b = *(const bf16x8*)(Bl + ((col * 128 + h * 16 + s * 32) ^ ((col & 7) << 4)));
                acc[t] = __builtin_amdgcn_mfma_f32_32x32x16_bf16(a, b, acc[t], 0, 0, 0);
            }
        }

        // ---- epilogue: dval, 128B-line stores, row/col mins ----
        const int rbase = rg * 32 + 4 * h;
        float cmv[4] = {INFINITY, INFINITY, INFINITY, INFINITY};
        const size_t latrow0 = (size_t)blockIdx.x * 256 + it * 64;
        #pragma unroll
        for (int i = 0; i < 16; ++i) {
            const int rl = rbase + (i & 3) + 8 * (i >> 2);
            const float xxv = xx_lds[rl];
            float rv = INFINITY;
            float* lrow = lat + (latrow0 + rl) * 512 + cg * 128 + lc;
            #pragma unroll
            for (int t = 0; t < 4; ++t) {
                const float dv = xxv + ppc[t] - 2.f * acc[t][i];
                lrow[t * 32] = dv;
                rv = fminf(rv, dv);
                cmv[t] = fminf(cmv[t], dv);
            }
            rv = fminf(rv, __shfl_xor(rv, 8, 64));
            rv = fminf(rv, __shfl_xor(rv, 16, 64));
            if (lc < 8) atomicMin(&rowmin_lds[rl], __float_as_int(rv));
        }
        #pragma unroll
        for (int t = 0; t < 4; ++t) {
            const float c = fminf(cmv[t], __shfl_xor(cmv[t], 32, 64));
            if (h == 0) atomicMin(&cmin_lds[cg * 128 + t * 32 + lc], __float_as_int(c));
        }
        __syncthreads();                       // barrier B

        // ---- per-iter row-min sum (wave 0); reset slots before next iter ----
        if (tid < 64) {
            float r = __int_as_float(rowmin_lds[tid]);
            rowmin_lds[tid] = INF_BITS;        // reset precedes barrier A(it+1)
            #pragma unroll
            for (int sh = 1; sh < 64; sh <<= 1) r += __shfl_xor(r, sh, 64);
            if (tid == 0) rsum_lds[0] += r;
        }
    }
    __syncthreads();
    atomicMin(&colmin_g[tid], cmin_lds[tid]);
    if (tid == 0) atomicAdd(&acc_g[0], rsum_lds[0]);
}

// ---------------- finalize: scalars --------------------------------------
__global__ __launch_bounds__(512) void finalize_kernel(const int* __restrict__ colmin,
                                                       const float* __restrict__ acc,
                                                       float* __restrict__ out) {
    const int t  = threadIdx.x;
    const int ln = t & 63, wv = t >> 6;
    float s = __int_as_float(colmin[t]);
    #pragma unroll
    for (int sh = 1; sh < 64; sh <<= 1) s += __shfl_xor(s, sh, 64);
    __shared__ float sm[8];
    if (ln == 0) sm[wv] = s;
    __syncthreads();
    if (t == 0) {
        float tot = 0.f;
        #pragma unroll
        for (int q = 0; q < 8; ++q) tot += sm[q];
        out[OUT_R1] = tot / 512.f;
        out[OUT_R2] = acc[0] / 131072.f;
        out[OUT_R3] = acc[1] / 512.f;
    }
}

extern "C" void kernel_launch(void* const* d_in, const int* in_sizes, int n_in,
                              void* d_out, int out_size, void* d_ws, size_t ws_size,
                              hipStream_t stream) {
    const float* x = (const float*)d_in[0];
    const float* p = (const float*)d_in[1];
    float* out = (float*)d_out;
    int*   colmin = (int*)d_ws;                       // [512] ints
    float* acc    = (float*)d_ws + 512;               // [2]
    float* PP     = (float*)d_ws + 1024;              // [512]
    unsigned char* Bbf = (unsigned char*)((float*)d_ws + 4096);  // 64KB, 16B aligned
    float* lat    = out + OUT_LAT;

    hipLaunchKernelGGL(init_kernel,     dim3(1),   dim3(512), 0, stream, colmin, acc);
    hipLaunchKernelGGL(proto_kernel,    dim3(512), dim3(256), 0, stream, p, PP, acc, Bbf);
    hipLaunchKernelGGL(main_kernel,     dim3(512), dim3(512), 0, stream,
                       x, (const uint4*)Bbf, PP, out, lat, colmin, acc);
    hipLaunchKernelGGL(finalize_kernel, dim3(1),   dim3(512), 0, stream, colmin, acc, out);
}